// Round 5
// baseline (1578.013 us; speedup 1.0000x reference)
//
#include <hip/hip_runtime.h>

#define N_NODES   50000
#define N_EDGES   1600000
#define N_FEAT    512
#define N_HID     128
#define NUM_GRAPHS 128
#define N_WAVES_GEMM 3125     // 50000/16 rows per wave

#define NBUCK 391             // ceil(50000/128) buckets of 128 dst nodes
#define EPB   6400            // edges per bin block
#define BIN_BLOCKS 250        // N_EDGES / EPB
#define PREP_DINV_BLOCKS 196  // ceil(50000/256)

typedef short bf16x8 __attribute__((ext_vector_type(8)));
typedef float f32x4  __attribute__((ext_vector_type(4)));

static __device__ __forceinline__ unsigned short f2bf(float f) {
  union { float f; unsigned int u; } v; v.f = f;
  unsigned int u = v.u;
  unsigned int r = (u + 0x7FFFu + ((u >> 16) & 1u)) >> 16;   // RNE
  return (unsigned short)r;
}
static __device__ __forceinline__ float bf2f(unsigned int bits16) {
  union { unsigned int u; float f; } v; v.u = bits16 << 16; return v.f;
}

// ---------------- init: zero cnt / pooled ----------------
__global__ void init_ws(int* __restrict__ cnt, int* __restrict__ pooled) {
  int i = blockIdx.x * 256 + threadIdx.x;
  if (i < N_NODES) cnt[i] = 0;
  if (i < NUM_GRAPHS * N_HID) pooled[i] = 0;
}

// ---------------- degree count over dst ----------------
__global__ void count_deg(const int* __restrict__ edge, int* __restrict__ cnt) {
  int e = blockIdx.x * 256 + threadIdx.x;
  if (e < N_EDGES) atomicAdd(&cnt[edge[N_EDGES + e]], 1);
}

// ------- prep: dinv + bucket sums (blocks 0..195) | wconv (blocks 196..451) -------
__global__ __launch_bounds__(256) void prep(const int* __restrict__ cnt,
                                            float* __restrict__ dinv,
                                            int* __restrict__ bucket_cnt,
                                            const float* __restrict__ W,
                                            unsigned short* __restrict__ wT) {
  if (blockIdx.x < PREP_DINV_BLOCKS) {
    __shared__ int red[256];
    int t = threadIdx.x;
    int node = blockIdx.x * 256 + t;
    int c = 0;
    if (node < N_NODES) {
      c = cnt[node];
      dinv[node] = rsqrtf((float)(c + 1));
    }
    red[t] = c;
    __syncthreads();
    for (int d = 64; d > 0; d >>= 1) {
      if ((t & 127) < d) red[t] += red[t + d];
      __syncthreads();
    }
    int b2 = blockIdx.x * 2;
    if (t == 0) bucket_cnt[b2] = red[0];
    if (t == 128 && b2 + 1 < NBUCK) bucket_cnt[b2 + 1] = red[128];
  } else {
    int i = (blockIdx.x - PREP_DINV_BLOCKS) * 256 + threadIdx.x;
    if (i < N_HID * N_FEAT) {
      int n = i >> 9, k = i & 511;
      wT[i] = f2bf(W[(size_t)k * N_HID + n]);
    }
  }
}

// ---------------- exclusive scan of bucket_cnt (391), 1 block ----------------
__global__ __launch_bounds__(256) void bucket_scan(const int* __restrict__ bucket_cnt,
                                                   int* __restrict__ bucket_base,
                                                   int* __restrict__ gcursor) {
  __shared__ int tsum[256];
  int t = threadIdx.x;
  int i0 = 2 * t, i1 = 2 * t + 1;
  int v0 = (i0 < NBUCK) ? bucket_cnt[i0] : 0;
  int v1 = (i1 < NBUCK) ? bucket_cnt[i1] : 0;
  tsum[t] = v0 + v1;
  __syncthreads();
  for (int d = 1; d < 256; d <<= 1) {
    int add = (t >= d) ? tsum[t - d] : 0;
    __syncthreads();
    tsum[t] += add;
    __syncthreads();
  }
  int excl = tsum[t] - (v0 + v1);
  if (i0 < NBUCK) { bucket_base[i0] = excl;      gcursor[i0] = excl; }
  if (i1 < NBUCK) { bucket_base[i1] = excl + v0; gcursor[i1] = excl + v0; }
}

// -------- bin_edges v2: LDS-staged bucket-sorted scatter, coalesced writes -------
// record: src | dst<<16  (both < 65536)
__global__ __launch_bounds__(256) void bin_edges(const int* __restrict__ edge,
                                                 int* __restrict__ gcursor,
                                                 unsigned int* __restrict__ brec) {
  __shared__ unsigned int recs[EPB];        // 25.6 KB
  __shared__ int lcnt[NBUCK], lbase[NBUCK], lscan[NBUCK], lcur[NBUCK];
  __shared__ int tsum[256];
  const int t = threadIdx.x;
  const int e0 = blockIdx.x * EPB;

  for (int b = t; b < NBUCK; b += 256) lcnt[b] = 0;
  __syncthreads();
  // pass 1: count buckets
  for (int e = e0 + t; e < e0 + EPB; e += 256)
    atomicAdd(&lcnt[edge[N_EDGES + e] >> 7], 1);
  __syncthreads();
  // local exclusive scan (391 entries, 2 per thread)
  int i0 = 2 * t, i1 = 2 * t + 1;
  int v0 = (i0 < NBUCK) ? lcnt[i0] : 0;
  int v1 = (i1 < NBUCK) ? lcnt[i1] : 0;
  tsum[t] = v0 + v1;
  __syncthreads();
  for (int d = 1; d < 256; d <<= 1) {
    int add = (t >= d) ? tsum[t - d] : 0;
    __syncthreads();
    tsum[t] += add;
    __syncthreads();
  }
  int excl = tsum[t] - (v0 + v1);
  if (i0 < NBUCK) lscan[i0] = excl;
  if (i1 < NBUCK) lscan[i1] = excl + v0;
  // reserve global space + zero cursors
  for (int b = t; b < NBUCK; b += 256) {
    int c = lcnt[b];
    lbase[b] = c ? atomicAdd(&gcursor[b], c) : 0;
    lcur[b] = 0;
  }
  __syncthreads();
  // pass 2: place into LDS at bucket-sorted local position
  for (int e = e0 + t; e < e0 + EPB; e += 256) {
    unsigned int s = (unsigned int)edge[e];
    unsigned int d = (unsigned int)edge[N_EDGES + e];
    int b = d >> 7;
    int pos = lscan[b] + atomicAdd(&lcur[b], 1);
    recs[pos] = s | (d << 16);
  }
  __syncthreads();
  // pass 3: dense coalesced write-out
  for (int i = t; i < EPB; i += 256) {
    unsigned int r = recs[i];
    int b = r >> 23;
    brec[lbase[b] + (i - lscan[b])] = r;
  }
}

// ---------------- GEMM: h'(bf16)[N,128] = dinv * (x[N,512] @ W1) via MFMA --------
__global__ __launch_bounds__(256) void gemm_mfma(const float* __restrict__ x,
                                                 const unsigned short* __restrict__ wT,
                                                 const float* __restrict__ dinv,
                                                 unsigned short* __restrict__ h) {
  const int wave = (blockIdx.x * 256 + threadIdx.x) >> 6;
  if (wave >= N_WAVES_GEMM) return;
  const int lane = threadIdx.x & 63;
  const int row0 = wave * 16;
  const int arow = row0 + (lane & 15);
  const int kbase = (lane >> 4) * 8;

  f32x4 acc[8];
#pragma unroll
  for (int i = 0; i < 8; i++) acc[i] = (f32x4){0.f, 0.f, 0.f, 0.f};

  for (int k0 = 0; k0 < N_FEAT; k0 += 32) {
    const float* ap = x + (size_t)arow * N_FEAT + k0 + kbase;
    float4 a0 = *(const float4*)ap;
    float4 a1 = *(const float4*)(ap + 4);
    bf16x8 af;
    af[0] = (short)f2bf(a0.x); af[1] = (short)f2bf(a0.y);
    af[2] = (short)f2bf(a0.z); af[3] = (short)f2bf(a0.w);
    af[4] = (short)f2bf(a1.x); af[5] = (short)f2bf(a1.y);
    af[6] = (short)f2bf(a1.z); af[7] = (short)f2bf(a1.w);

#pragma unroll
    for (int ct = 0; ct < 8; ct++) {
      const bf16x8 bf = *(const bf16x8*)(wT + (size_t)(ct * 16 + (lane & 15)) * N_FEAT
                                            + k0 + kbase);
      acc[ct] = __builtin_amdgcn_mfma_f32_16x16x32_bf16(af, bf, acc[ct], 0, 0, 0);
    }
  }

  float dvv[4];
#pragma unroll
  for (int r = 0; r < 4; r++) dvv[r] = dinv[row0 + (lane >> 4) * 4 + r];
#pragma unroll
  for (int ct = 0; ct < 8; ct++) {
#pragma unroll
    for (int r = 0; r < 4; r++) {
      int row = row0 + (lane >> 4) * 4 + r;
      int col = ct * 16 + (lane & 15);
      h[(size_t)row * N_HID + col] = f2bf(acc[ct][r] * dvv[r]);
    }
  }
}

// -------- bucket_agg: per-bucket LDS fp32 accumulation + finalize + pool --------
// 1 block = 1 bucket (128 dst nodes), 512 threads = 8 waves, 64KB+ LDS acc.
__global__ __launch_bounds__(512) void bucket_agg(
    const unsigned short* __restrict__ h, const unsigned int* __restrict__ brec,
    const int* __restrict__ bucket_base, const int* __restrict__ bucket_cnt,
    const float* __restrict__ dinv, const float* __restrict__ b1,
    const int* __restrict__ batch, int* __restrict__ pooled) {
  __shared__ float acc[129][N_HID];      // row 128 = dummy for padded records
  __shared__ int rmaxi[2][N_HID];
  const int t = threadIdx.x;
  const int wv = t >> 6;
  const int lane = t & 63;
  const int f2 = lane * 2;
  const int bb = blockIdx.x;
  const int nbase = bb << 7;

  for (int i = t; i < 129 * N_HID; i += 512) (&acc[0][0])[i] = 0.f;
  if (t < 256) rmaxi[t >> 7][t & 127] = 0;
  __syncthreads();

  const int base = bucket_base[bb];
  const int nb = bucket_cnt[bb];
  const unsigned int padrec = (unsigned int)(nbase + 128) << 16;

  // edge accumulation: strips of 512 (64 per wave), padded to full 64
  for (int s0 = wv * 64; s0 < nb; s0 += 512) {
    int idx = s0 + lane;
    unsigned int rl = (idx < nb) ? brec[base + idx] : padrec;
#pragma unroll
    for (int u8 = 0; u8 < 64; u8 += 8) {
      unsigned int rr[8], qq[8];
#pragma unroll
      for (int u = 0; u < 8; u++) rr[u] = (unsigned int)__shfl((int)rl, u8 + u);
#pragma unroll
      for (int u = 0; u < 8; u++)
        qq[u] = *(const unsigned int*)(h + (size_t)(rr[u] & 0xFFFFu) * N_HID + f2);
#pragma unroll
      for (int u = 0; u < 8; u++) {
        int dl = (int)(rr[u] >> 16) - nbase;      // 0..127 real, 128 pad
        atomicAdd(&acc[dl][f2],     bf2f(qq[u] & 0xFFFFu));
        atomicAdd(&acc[dl][f2 + 1], bf2f(qq[u] >> 16));
      }
    }
  }
  __syncthreads();

  // finalize: self-loop + dinv[dst] + bias + relu + per-graph LDS max
  const float bb0 = b1[f2], bb1 = b1[f2 + 1];
  const int g0 = batch[nbase];
#pragma unroll 4
  for (int k = 0; k < 16; k++) {
    int dl = wv * 16 + k;
    int node = nbase + dl;
    if (node < N_NODES) {
      unsigned int p = *(const unsigned int*)(h + (size_t)node * N_HID + f2);
      float dv = dinv[node];
      float v0 = fmaxf(fmaf(acc[dl][f2]     + bf2f(p & 0xFFFFu), dv, bb0), 0.f);
      float v1 = fmaxf(fmaf(acc[dl][f2 + 1] + bf2f(p >> 16),     dv, bb1), 0.f);
      int slot = batch[node] - g0;
      atomicMax(&rmaxi[slot][f2],     __float_as_int(v0));
      atomicMax(&rmaxi[slot][f2 + 1], __float_as_int(v1));
    }
  }
  __syncthreads();

  if (t < 256) {
    int slot = t >> 7, f = t & 127;
    int lastnode = nbase + 127 < N_NODES ? nbase + 127 : N_NODES - 1;
    int g1 = batch[lastnode];
    if (slot == 0)
      atomicMax(&pooled[g0 * N_HID + f], rmaxi[0][f]);
    else if (g1 != g0)
      atomicMax(&pooled[g1 * N_HID + f], rmaxi[1][f]);
  }
}

// ---------------- head: logits + log_softmax ----------------
__global__ __launch_bounds__(128) void head_kernel(const int* __restrict__ pooled,
                                                   const float* __restrict__ W2,
                                                   const float* __restrict__ b2,
                                                   float* __restrict__ out) {
  __shared__ float sW[N_HID * 2];
  int t = threadIdx.x;
  sW[t] = W2[t];
  sW[t + 128] = W2[t + 128];
  __syncthreads();
  float l0 = b2[0], l1 = b2[1];
  for (int f = 0; f < N_HID; f++) {
    float pv = __int_as_float(pooled[t * N_HID + f]);
    l0 = fmaf(pv, sW[f * 2 + 0], l0);
    l1 = fmaf(pv, sW[f * 2 + 1], l1);
  }
  float m = fmaxf(l0, l1);
  float lse = m + logf(expf(l0 - m) + expf(l1 - m));
  out[t * 2 + 0] = l0 - lse;
  out[t * 2 + 1] = l1 - lse;
}

extern "C" void kernel_launch(void* const* d_in, const int* in_sizes, int n_in,
                              void* d_out, int out_size, void* d_ws, size_t ws_size,
                              hipStream_t stream) {
  const float* x   = (const float*)d_in[0];
  const float* W1  = (const float*)d_in[1];
  const float* b1  = (const float*)d_in[2];
  const float* W2  = (const float*)d_in[3];
  const float* b2  = (const float*)d_in[4];
  const int* edge  = (const int*)d_in[5];
  const int* batch = (const int*)d_in[6];
  float* out = (float*)d_out;

  char* ws = (char*)d_ws;
  int*   cnt         = (int*)(ws + 0);          // 200 KB
  float* dinv        = (float*)(ws + 200704);   // 200 KB
  int*   pooled      = (int*)(ws + 401408);     // 64 KB
  int*   bucket_cnt  = (int*)(ws + 466944);     // 2 KB
  int*   bucket_base = (int*)(ws + 468992);     // 2 KB
  int*   gcursor     = (int*)(ws + 471040);     // 2 KB
  unsigned int* brec = (unsigned int*)(ws + 473088);     // 6.4 MB
  unsigned short* h  = (unsigned short*)(ws + 6873088);  // 12.8 MB
  unsigned short* wT = (unsigned short*)(ws + 19673088); // 128 KB

  init_ws<<<196, 256, 0, stream>>>(cnt, pooled);
  count_deg<<<N_EDGES / 256, 256, 0, stream>>>(edge, cnt);
  prep<<<PREP_DINV_BLOCKS + 256, 256, 0, stream>>>(cnt, dinv, bucket_cnt, W1, wT);
  bucket_scan<<<1, 256, 0, stream>>>(bucket_cnt, bucket_base, gcursor);
  bin_edges<<<BIN_BLOCKS, 256, 0, stream>>>(edge, gcursor, brec);
  gemm_mfma<<<(N_WAVES_GEMM + 3) / 4, 256, 0, stream>>>(x, wT, dinv, h);
  bucket_agg<<<NBUCK, 512, 0, stream>>>(h, brec, bucket_base, bucket_cnt, dinv, b1, batch, pooled);
  head_kernel<<<1, 128, 0, stream>>>(pooled, W2, b2, out);
}